// Round 6
// baseline (180.026 us; speedup 1.0000x reference)
//
#include <hip/hip_runtime.h>

// Segment-mean + ReLU pooling, R5: single main kernel, fused finalize.
//
// History: R0-R2 (~89us) capped at ~5 TB/s regardless of read pattern;
// R3 counters exposed L3 retaining half of d_in across replays (FETCH ~202MB)
// -> swiss-cheese HBM miss stream. R4 (nt loads, no atomics, ws+gather,
// 2 kernels) = 78.45us; accum ~= 94% of 6.3 TB/s copy ceiling. R5 removes
// the remaining structural overhead: the separate gather dispatch.
//
// Structure: one memset node (ws: [G*512] f32 deposit area + [G] i32
// counters), then one kernel. 1024 blocks own fixed 196-row chunks (balanced);
// per sub-segment they deposit partial sums into ws via atomicAdd (device-
// coherent), then bump cnt[s]; the LAST contributor for segment s finalizes:
// agent-scope atomic loads of the deposits, scale by 1/count, relu, store to
// d_out. All cross-block communication is via atomics -> no dependence on
// cross-XCD L2 coherence of plain accesses. Deterministic up to fp atomic
// ordering (<1e-5 here; threshold 2.3e-2).

#define D_FEAT 512
#define NCOL4 (D_FEAT / 4)  // 128 float4 columns

typedef float f4 __attribute__((ext_vector_type(4)));

__global__ __launch_bounds__(512) void seg_pool_fused(
    const f4* __restrict__ in,    // [num_nodes, NCOL4]
    const int* __restrict__ idx,  // [num_graphs]
    float* __restrict__ acc,      // ws deposit area [num_graphs, D_FEAT], zeroed
    int* __restrict__ cnt,        // ws counters [num_graphs], zeroed
    float* __restrict__ out,      // [num_graphs, D_FEAT]
    int num_nodes, int num_graphs, int rpb) {
  const int b = blockIdx.x;
  const int r0 = b * rpb;
  if (r0 >= num_nodes) return;
  const int r1 = min(r0 + rpb, num_nodes);

  const int lane = threadIdx.x & 63;
  const int w = threadIdx.x >> 6;  // wave 0..7
  const int t = threadIdx.x;

  __shared__ f4 part[8][NCOL4];  // 16 KB
  __shared__ int done;

  // largest s with idx[s] <= r0 (block-uniform; idx 4KB, cache-hot)
  int lo = 0, hi = num_graphs - 1;
  while (lo < hi) {
    int mid = (lo + hi + 1) >> 1;
    if (idx[mid] <= r0) lo = mid;
    else hi = mid - 1;
  }
  int s = lo;
  int row = r0;

  while (row < r1) {
    const int seg_end = (s + 1 < num_graphs) ? idx[s + 1] : num_nodes;
    const int e = min(seg_end, r1);
    const int n = e - row;

    // --- accumulate: wave w streams contiguous rows [wsr, wer) flat ---
    const int wsr = row + (n * w) / 8;
    const int wer = row + (n * (w + 1)) / 8;

    f4 accA = {0.f, 0.f, 0.f, 0.f};  // even 64-blocks -> col lane
    f4 accB = {0.f, 0.f, 0.f, 0.f};  // odd  64-blocks -> col lane+64

    int j = wsr * NCOL4 + lane;
    const int jend = wer * NCOL4;
    for (; j + 448 < jend; j += 512) {  // 8 independent nt loads in flight
      f4 v0 = __builtin_nontemporal_load(&in[j]);
      f4 v1 = __builtin_nontemporal_load(&in[j + 64]);
      f4 v2 = __builtin_nontemporal_load(&in[j + 128]);
      f4 v3 = __builtin_nontemporal_load(&in[j + 192]);
      f4 v4 = __builtin_nontemporal_load(&in[j + 256]);
      f4 v5 = __builtin_nontemporal_load(&in[j + 320]);
      f4 v6 = __builtin_nontemporal_load(&in[j + 384]);
      f4 v7 = __builtin_nontemporal_load(&in[j + 448]);
      accA += v0; accB += v1; accA += v2; accB += v3;
      accA += v4; accB += v5; accA += v6; accB += v7;
    }
    for (; j < jend; j += 64) {
      f4 v = __builtin_nontemporal_load(&in[j]);
      if ((((j - lane) >> 6) & 1) == 0) accA += v;
      else accB += v;
    }

    part[w][lane] = accA;
    part[w][lane + 64] = accB;
    __syncthreads();

    // --- deposit partial row into ws accumulator (device-coherent atomics) ---
    if (t < NCOL4) {
      f4 a = part[0][t];
#pragma unroll
      for (int ww = 1; ww < 8; ++ww) a += part[ww][t];
      float* o = acc + (size_t)s * D_FEAT + t * 4;
      atomicAdd(o + 0, a.x);
      atomicAdd(o + 1, a.y);
      atomicAdd(o + 2, a.z);
      atomicAdd(o + 3, a.w);
    }
    __syncthreads();  // deposits complete (vmcnt drained) before gating

    // --- completion gate: last contributor finalizes segment s ---
    const int seg_start = idx[s];
    const int needed = (seg_end - 1) / rpb - seg_start / rpb + 1;
    if (t == 0) {
      int old = __hip_atomic_fetch_add(&cnt[s], 1, __ATOMIC_ACQ_REL,
                                       __HIP_MEMORY_SCOPE_AGENT);
      done = (old == needed - 1);
    }
    __syncthreads();

    if (done) {
      const float inv = 1.0f / (float)(seg_end - seg_start);
      float v = __hip_atomic_load(&acc[(size_t)s * D_FEAT + t],
                                  __ATOMIC_RELAXED, __HIP_MEMORY_SCOPE_AGENT);
      out[(size_t)s * D_FEAT + t] = fmaxf(v * inv, 0.f);
    }
    // next iteration's writes to part[]/done are separated from these reads
    // by the __syncthreads() after the next accumulate phase.

    row = e;
    ++s;
  }
}

extern "C" void kernel_launch(void* const* d_in, const int* in_sizes, int n_in,
                              void* d_out, int out_size, void* d_ws,
                              size_t ws_size, hipStream_t stream) {
  const f4* in = (const f4*)d_in[0];
  const int* idx = (const int*)d_in[1];
  float* out = (float*)d_out;

  const int num_nodes = in_sizes[0] / D_FEAT;  // 200000
  const int num_graphs = in_sizes[1];          // 1024

  // ws layout: [num_graphs*D_FEAT] f32 deposit area | [num_graphs] i32 counters
  float* acc = (float*)d_ws;
  int* cnt = (int*)((char*)d_ws + (size_t)num_graphs * D_FEAT * sizeof(float));
  const size_t zero_bytes =
      (size_t)num_graphs * D_FEAT * sizeof(float) + num_graphs * sizeof(int);
  hipMemsetAsync(d_ws, 0, zero_bytes, stream);

  const int nblocks = 1024;  // 4 equal chunks per CU
  const int rpb = (num_nodes + nblocks - 1) / nblocks;  // 196

  seg_pool_fused<<<dim3(nblocks), dim3(512), 0, stream>>>(
      in, idx, acc, cnt, out, num_nodes, num_graphs, rpb);
}

// Round 7
// 91.331 us; speedup vs baseline: 1.9711x; 1.9711x over previous
//
#include <hip/hip_runtime.h>

// Segment-mean + ReLU pooling, R6: L3-pinned half + NT-streamed half.
//
// History: R0-R2 ~89us (L3 retains a random half of d_in across replays ->
// swiss-cheese HBM misses cap reads ~5 TB/s). R4: nt loads everywhere +
// ws deposits + gather = 78.45us (~94% of copy ceiling). R5: fused finalize
// with ACQ_REL agent atomics = 180us REGRESSION (cache-maintenance ops per
// sub-segment nuke L2) -- reverted; no ordered atomics in hot kernels.
//
// R6 theory: exploit the L3 retention R3 exposed, deliberately. Rows are
// split spatially: blocks b < BSPLIT (first ~47% of rows, ~193MB -- fits in
// 256MB L3 with ws+out) use PLAIN temporal loads -> steady-state L3 hits;
// remaining rows use NT loads -> single contiguous HBM stream, evict-first
// so it never displaces the pinned half. L3 and HBM serve in parallel ->
// effective read BW above HBM-only. 4096 blocks (rpb=49) so early-finishing
// pinned blocks are backfilled by the scheduler.
//
// Per-chunk sub-segments <= 3 for ANY rpb: consecutive segment sizes sum
// >= 197 > rpb, so at most 2 segment starts strictly inside a chunk.
// Deposits: plain stores to ws[chunk][local(0..2)][512] (every slot gather
// reads is written the same replay -> no zeroing, no atomics).

#define D_FEAT 512
#define NCOL4 (D_FEAT / 4)  // 128 float4 columns
#define NBLK 4096
#define BSPLIT 1920  // blocks 0..1919 pinned (94080 rows = 192.7MB)

typedef float f4 __attribute__((ext_vector_type(4)));

__device__ __forceinline__ int find_seg(const int* __restrict__ idx, int G,
                                        int r) {
  int lo = 0, hi = G - 1;
  while (lo < hi) {
    int mid = (lo + hi + 1) >> 1;
    if (idx[mid] <= r) lo = mid;
    else hi = mid - 1;
  }
  return lo;
}

__global__ __launch_bounds__(512) void seg_accum_ws(
    const f4* __restrict__ in,    // [num_nodes, NCOL4]
    const int* __restrict__ idx,  // [num_graphs]
    float* __restrict__ ws,       // [NBLK, 3, D_FEAT]
    int num_nodes, int num_graphs, int rpb) {
  const int b = blockIdx.x;
  const int r0 = b * rpb;
  if (r0 >= num_nodes) return;
  const int r1 = min(r0 + rpb, num_nodes);

  const int lane = threadIdx.x & 63;
  const int w = threadIdx.x >> 6;  // wave 0..7
  const int t = threadIdx.x;

  __shared__ f4 part[8][NCOL4];  // 16 KB

  const int s0 = find_seg(idx, num_graphs, r0);
  const int e1 = (s0 + 1 < num_graphs) ? idx[s0 + 1] : num_nodes;
  const int e2 = (s0 + 2 < num_graphs) ? idx[s0 + 2] : num_nodes;
  const int B1 = min(e1, r1) * NCOL4;  // f4-index bucket boundaries
  const int B2 = min(e2, r1) * NCOL4;

  // wave w owns 64-f4-aligned contiguous span of the chunk
  const int n = r1 - r0;
  const int u0 = (2 * n * w) >> 3;        // in 64-f4 units
  const int u1 = (2 * n * (w + 1)) >> 3;
  const int js = r0 * NCOL4 + u0 * 64;    // 64-aligned f4 index
  const int nb = u1 - u0;                 // 64-f4 blocks in span

  // even-slot blocks -> col cE, odd-slot -> cO (parity from u0; r0*2 even)
  const int cE = lane ^ ((u0 & 1) << 6);
  const int cO = cE ^ 64;

  f4 z = {0.f, 0.f, 0.f, 0.f};
  f4 aE0 = z, aE1 = z, aE2 = z, aO0 = z, aO1 = z, aO2 = z;

#define ACC3(v, jb, a0, a1, a2)            \
  {                                        \
    bool x1 = (jb) >= B1, x2 = (jb) >= B2; \
    a0 += x1 ? z : (v);                    \
    a1 += (x1 && !x2) ? (v) : z;           \
    a2 += x2 ? (v) : z;                    \
  }

#define STREAM(LD)                                        \
  {                                                       \
    int k = 0;                                            \
    for (; k + 4 <= nb; k += 4) {                         \
      const int jb = js + k * 64;                         \
      const f4* p = in + jb + lane;                       \
      f4 v0 = LD(p);                                      \
      f4 v1 = LD(p + 64);                                 \
      f4 v2 = LD(p + 128);                                \
      f4 v3 = LD(p + 192);                                \
      ACC3(v0, jb, aE0, aE1, aE2);                        \
      ACC3(v1, jb + 64, aO0, aO1, aO2);                   \
      ACC3(v2, jb + 128, aE0, aE1, aE2);                  \
      ACC3(v3, jb + 192, aO0, aO1, aO2);                  \
    }                                                     \
    for (; k < nb; ++k) {                                 \
      const int jb = js + k * 64;                         \
      f4 v = LD((in + jb + lane));                        \
      if ((k & 1) == 0) ACC3(v, jb, aE0, aE1, aE2)        \
      else ACC3(v, jb, aO0, aO1, aO2)                     \
    }                                                     \
  }

#define LD_PLAIN(p) (*(p))
#define LD_NT(p) (__builtin_nontemporal_load(p))

  if (b < BSPLIT) {
    STREAM(LD_PLAIN)
  } else {
    STREAM(LD_NT)
  }

#define ROUND(K, aE, aO)                                  \
  {                                                       \
    part[w][cE] = aE;                                     \
    part[w][cO] = aO;                                     \
    __syncthreads();                                      \
    if (t < NCOL4) {                                      \
      f4 a = part[0][t];                                  \
      _Pragma("unroll") for (int ww = 1; ww < 8; ++ww)    \
          a += part[ww][t];                               \
      ((f4*)ws)[((size_t)b * 3 + K) * NCOL4 + t] = a;     \
    }                                                     \
  }

  ROUND(0, aE0, aO0)
  if (e1 < r1) {
    __syncthreads();
    ROUND(1, aE1, aO1)
  }
  if (e2 < r1) {
    __syncthreads();
    ROUND(2, aE2, aO2)
  }
}

__global__ __launch_bounds__(512) void seg_gather(
    const float* __restrict__ ws, const int* __restrict__ idx,
    float* __restrict__ out, int num_nodes, int num_graphs, int rpb) {
  const int s = blockIdx.x;  // one block per segment
  if (s >= num_graphs) return;
  const int t = threadIdx.x;  // one float column
  const int start = idx[s];
  const int end = (s + 1 < num_graphs) ? idx[s + 1] : num_nodes;
  const int b0 = start / rpb;
  const int b1 = (end - 1) / rpb;

  float sum = 0.f;
  for (int bb = b0; bb <= b1; ++bb) {
    const int c = s - find_seg(idx, num_graphs, bb * rpb);
    if (c >= 0 && c < 3) sum += ws[((size_t)bb * 3 + c) * D_FEAT + t];
  }
  out[(size_t)s * D_FEAT + t] = fmaxf(sum / (float)(end - start), 0.f);
}

extern "C" void kernel_launch(void* const* d_in, const int* in_sizes, int n_in,
                              void* d_out, int out_size, void* d_ws,
                              size_t ws_size, hipStream_t stream) {
  const f4* in = (const f4*)d_in[0];
  const int* idx = (const int*)d_in[1];
  float* out = (float*)d_out;
  float* ws = (float*)d_ws;  // 4096*3*512*4B = 25 MB << ws_size

  const int num_nodes = in_sizes[0] / D_FEAT;  // 200000
  const int num_graphs = in_sizes[1];          // 1024

  const int rpb = (num_nodes + NBLK - 1) / NBLK;  // 49

  seg_accum_ws<<<dim3(NBLK), dim3(512), 0, stream>>>(in, idx, ws, num_nodes,
                                                     num_graphs, rpb);
  seg_gather<<<dim3(num_graphs), dim3(512), 0, stream>>>(ws, idx, out,
                                                         num_nodes, num_graphs,
                                                         rpb);
}

// Round 8
// 82.214 us; speedup vs baseline: 2.1897x; 1.1109x over previous
//
#include <hip/hip_runtime.h>

// Segment-mean + ReLU pooling, R7: R4 streaming core + fused finalize via
// RELAXED device atomics only.
//
// History: R0-R2 ~89us (read-pattern-invariant; L3 retains a random half of
// d_in across replays -> swiss-cheese HBM misses). R4 = 78.45us: NT loads
// (evict-first, contiguous miss stream), ws partials, separate gather.
// R5 = 180us REGRESSION: fused finalize gated by ACQ_REL agent atomics ->
// per-sub-segment buffer_wbl2/buffer_inv L2 maintenance. R6 = 91us
// REGRESSION: L3-pinning split (residency not schedulable; predicated inner
// loop 3x VALU). Lesson: R4 core is optimal; only the gather dispatch (~8us
// incl. gap) is recoverable.
//
// R7: fuse finalize with NO ordered atomics. All cross-block communication is
// relaxed device atomics (executed at the device coherence point, no cache
// maintenance): deposits = atomicAdd into zeroed acc; gate = relaxed
// fetch_add on cnt[s], ordered by __syncthreads()'s vmcnt(0) drain (deposit
// atomics complete at the coherence point before the gate bump issues);
// last contributor re-reads acc via relaxed agent atomic loads and writes
// relu(acc/count) to d_out. Deterministic up to fp atomic ordering (~1e-5,
// threshold 2.3e-2).

#define D_FEAT 512
#define NCOL4 (D_FEAT / 4)  // 128 float4 columns

typedef float f4 __attribute__((ext_vector_type(4)));

__global__ __launch_bounds__(512) void seg_pool_fused(
    const f4* __restrict__ in,    // [num_nodes, NCOL4]
    const int* __restrict__ idx,  // [num_graphs]
    float* __restrict__ acc,      // ws deposit area [num_graphs, D_FEAT], zeroed
    int* __restrict__ cnt,        // ws counters [num_graphs], zeroed
    float* __restrict__ out,      // [num_graphs, D_FEAT]
    int num_nodes, int num_graphs, int rpb) {
  const int b = blockIdx.x;
  const int r0 = b * rpb;
  if (r0 >= num_nodes) return;
  const int r1 = min(r0 + rpb, num_nodes);

  const int lane = threadIdx.x & 63;
  const int w = threadIdx.x >> 6;  // wave 0..7
  const int t = threadIdx.x;

  __shared__ f4 part[8][NCOL4];  // 16 KB
  __shared__ int done;

  // largest s with idx[s] <= r0 (block-uniform; idx 4KB, cache-hot)
  int lo = 0, hi = num_graphs - 1;
  while (lo < hi) {
    int mid = (lo + hi + 1) >> 1;
    if (idx[mid] <= r0) lo = mid;
    else hi = mid - 1;
  }
  int s = lo;
  int row = r0;

  while (row < r1) {
    const int seg_end = (s + 1 < num_graphs) ? idx[s + 1] : num_nodes;
    const int e = min(seg_end, r1);
    const int n = e - row;

    // --- accumulate: wave w streams contiguous rows [wsr, wer) flat (R4) ---
    const int wsr = row + (n * w) / 8;
    const int wer = row + (n * (w + 1)) / 8;

    f4 accA = {0.f, 0.f, 0.f, 0.f};  // even 64-blocks -> col lane
    f4 accB = {0.f, 0.f, 0.f, 0.f};  // odd  64-blocks -> col lane+64

    int j = wsr * NCOL4 + lane;
    const int jend = wer * NCOL4;
    for (; j + 448 < jend; j += 512) {  // 8 independent nt loads in flight
      f4 v0 = __builtin_nontemporal_load(&in[j]);
      f4 v1 = __builtin_nontemporal_load(&in[j + 64]);
      f4 v2 = __builtin_nontemporal_load(&in[j + 128]);
      f4 v3 = __builtin_nontemporal_load(&in[j + 192]);
      f4 v4 = __builtin_nontemporal_load(&in[j + 256]);
      f4 v5 = __builtin_nontemporal_load(&in[j + 320]);
      f4 v6 = __builtin_nontemporal_load(&in[j + 384]);
      f4 v7 = __builtin_nontemporal_load(&in[j + 448]);
      accA += v0; accB += v1; accA += v2; accB += v3;
      accA += v4; accB += v5; accA += v6; accB += v7;
    }
    for (; j < jend; j += 64) {
      f4 v = __builtin_nontemporal_load(&in[j]);
      if ((((j - lane) >> 6) & 1) == 0) accA += v;
      else accB += v;
    }

    part[w][lane] = accA;
    part[w][lane + 64] = accB;
    __syncthreads();

    // --- deposit partial row (relaxed device atomicAdd; R1-proven free) ---
    if (t < NCOL4) {
      f4 a = part[0][t];
#pragma unroll
      for (int ww = 1; ww < 8; ++ww) a += part[ww][t];
      float* o = acc + (size_t)s * D_FEAT + t * 4;
      atomicAdd(o + 0, a.x);
      atomicAdd(o + 1, a.y);
      atomicAdd(o + 2, a.z);
      atomicAdd(o + 3, a.w);
    }
    // vmcnt(0) drain inside barrier: deposits complete at the coherence
    // point before any thread proceeds to the gate bump.
    __syncthreads();

    // --- completion gate: RELAXED fetch_add (no cache maintenance) ---
    const int seg_start = idx[s];
    const int needed = (seg_end - 1) / rpb - seg_start / rpb + 1;
    if (t == 0) {
      int old = __hip_atomic_fetch_add(&cnt[s], 1, __ATOMIC_RELAXED,
                                       __HIP_MEMORY_SCOPE_AGENT);
      done = (old == needed - 1);
    }
    __syncthreads();

    if (done) {
      // last contributor: all deposits for s are at the coherence point.
      const float inv = 1.0f / (float)(seg_end - seg_start);
      float v = __hip_atomic_load(&acc[(size_t)s * D_FEAT + t],
                                  __ATOMIC_RELAXED, __HIP_MEMORY_SCOPE_AGENT);
      out[(size_t)s * D_FEAT + t] = fmaxf(v * inv, 0.f);
    }
    // next iteration: part[]/done rewritten only after the next barriers.

    row = e;
    ++s;
  }
}

extern "C" void kernel_launch(void* const* d_in, const int* in_sizes, int n_in,
                              void* d_out, int out_size, void* d_ws,
                              size_t ws_size, hipStream_t stream) {
  const f4* in = (const f4*)d_in[0];
  const int* idx = (const int*)d_in[1];
  float* out = (float*)d_out;

  const int num_nodes = in_sizes[0] / D_FEAT;  // 200000
  const int num_graphs = in_sizes[1];          // 1024

  // ws layout: [num_graphs*D_FEAT] f32 deposit area | [num_graphs] i32 counters
  float* acc = (float*)d_ws;
  int* cnt = (int*)((char*)d_ws + (size_t)num_graphs * D_FEAT * sizeof(float));
  const size_t zero_bytes =
      (size_t)num_graphs * D_FEAT * sizeof(float) + num_graphs * sizeof(int);
  hipMemsetAsync(d_ws, 0, zero_bytes, stream);

  const int nblocks = 1024;  // 4 equal chunks per CU, balanced
  const int rpb = (num_nodes + nblocks - 1) / nblocks;  // 196

  seg_pool_fused<<<dim3(nblocks), dim3(512), 0, stream>>>(
      in, idx, acc, cnt, out, num_nodes, num_graphs, rpb);
}

// Round 9
// 78.576 us; speedup vs baseline: 2.2911x; 1.0463x over previous
//
#include <hip/hip_runtime.h>

// Segment-mean + ReLU pooling, R8 == R4 (proven best: 78.45us), locked in.
//
// Final structure: NT streaming reads + ws partials + tiny gather kernel.
//
// Session ledger (what was tried, what the counters said):
//  R0 (89.9): 1 block/segment. Straggler-bound theory -> WRONG (R1 same).
//  R1 (88.8): balanced chunks + atomicAdd deposits. Plain device atomicAdd
//             proven free. Read BW stuck ~5 TB/s.
//  R2 (88.8): wave-contiguous streams, 4-deep MLP. IDENTICAL -> read pattern
//             is not the lever.
//  R3 (337, coop): grid.sync spin wrecks it, BUT counters exposed the cause
//             of the ~5 TB/s cap: FETCH_SIZE ~= 202MB = half the input. L3
//             (256MB) retains a pseudo-random half of d_in across graph
//             replays -> HBM miss stream is "swiss cheese" (alternating
//             absent lines), no DRAM page locality.
//  R4 (78.45): __builtin_nontemporal_load (evict-first) -> input never
//             pollutes L3, misses are contiguous streams; + no atomics,
//             no zero kernel. accum ~70us = 412MB @ 5.9 TB/s = 94% of the
//             6.29 TB/s measured copy ceiling (m13).
//  R5 (180):  fused finalize, ACQ_REL agent atomics -> buffer_wbl2/inv L2
//             maintenance per sub-segment. NEVER use ordered atomics in a
//             hot loop on multi-XCD CDNA.
//  R6 (91.3): L3-pinning split (plain loads for "resident" half) -> L3
//             residency is not schedulable from the kernel; predicated
//             3-bucket loop tripled VALU. REVERTED.
//  R7 (82.2): fused finalize, RELAXED atomics only -> correct & no cache
//             maintenance, but gate+tail work on laggard critical path costs
//             more than the saved dispatch (~8us). Two plain dispatches win.
//
// Roofline: 412MB / 6.29 TB/s = 65.5us + ~8us structure = ~73.5us floor;
// 78.45 is within 7%. Read-pattern changes are proven non-levers.

#define D_FEAT 512
#define NCOL4 (D_FEAT / 4)  // 128 float4 columns
#define MAX_SUB 4

typedef float f4 __attribute__((ext_vector_type(4)));

__global__ __launch_bounds__(512) void seg_accum_ws(
    const f4* __restrict__ in,   // [num_nodes, NCOL4]
    const int* __restrict__ idx, // [num_graphs]
    float* __restrict__ ws,      // [nblocks, MAX_SUB, D_FEAT]
    int num_nodes, int num_graphs, int rpb) {
  const int b = blockIdx.x;
  const int r0 = b * rpb;
  if (r0 >= num_nodes) return;
  const int r1 = min(r0 + rpb, num_nodes);

  const int lane = threadIdx.x & 63;
  const int w = threadIdx.x >> 6;  // wave 0..7

  __shared__ f4 part[8][NCOL4];  // 16 KB

  // largest s with idx[s] <= r0 (block-uniform; idx 4KB, cache-hot)
  int lo = 0, hi = num_graphs - 1;
  while (lo < hi) {
    int mid = (lo + hi + 1) >> 1;
    if (idx[mid] <= r0) lo = mid;
    else hi = mid - 1;
  }
  int s = lo;
  int row = r0;
  int k = 0;

  while (row < r1 && k < MAX_SUB) {
    const int seg_end = (s + 1 < num_graphs) ? idx[s + 1] : num_nodes;
    const int e = min(seg_end, r1);
    const int n = e - row;

    // wave w streams contiguous rows [wsr, wer) of this sub-segment, flat.
    // Dual accumulators track lane->column parity (even 64-f4 block -> col
    // lane, odd -> col lane+64).
    const int wsr = row + (n * w) / 8;
    const int wer = row + (n * (w + 1)) / 8;

    f4 accA = {0.f, 0.f, 0.f, 0.f};
    f4 accB = {0.f, 0.f, 0.f, 0.f};

    int j = wsr * NCOL4 + lane;
    const int jend = wer * NCOL4;
    for (; j + 192 < jend; j += 256) {  // 4 independent nt loads in flight
      f4 v0 = __builtin_nontemporal_load(&in[j]);
      f4 v1 = __builtin_nontemporal_load(&in[j + 64]);
      f4 v2 = __builtin_nontemporal_load(&in[j + 128]);
      f4 v3 = __builtin_nontemporal_load(&in[j + 192]);
      accA += v0;
      accB += v1;
      accA += v2;
      accB += v3;
    }
    for (; j < jend; j += 64) {
      f4 v = __builtin_nontemporal_load(&in[j]);
      if ((((j - lane) >> 6) & 1) == 0) accA += v;
      else accB += v;
    }

    part[w][lane] = accA;
    part[w][lane + 64] = accB;
    __syncthreads();

    if (threadIdx.x < NCOL4) {  // one float4 column per thread
      f4 a = part[0][threadIdx.x];
#pragma unroll
      for (int ww = 1; ww < 8; ++ww) a += part[ww][threadIdx.x];
      ((f4*)ws)[((size_t)b * MAX_SUB + k) * NCOL4 + threadIdx.x] = a;
    }
    __syncthreads();  // part[] reused next sub-segment

    row = e;
    ++s;
    ++k;
  }
}

__global__ __launch_bounds__(512) void seg_gather(
    const float* __restrict__ ws, const int* __restrict__ idx,
    float* __restrict__ out, int num_nodes, int num_graphs, int rpb) {
  const int s = blockIdx.x;  // one block per segment
  if (s >= num_graphs) return;
  const int t = threadIdx.x;  // one float column per thread
  const int start = idx[s];
  const int end = (s + 1 < num_graphs) ? idx[s + 1] : num_nodes;
  const int b0 = start / rpb;
  const int b1 = (end - 1) / rpb;

  float sum = 0.f;
  for (int bb = b0; bb <= b1; ++bb) {
    // first segment of block bb's chunk
    const int rr = bb * rpb;
    int lo = 0, hi = num_graphs - 1;
    while (lo < hi) {
      int mid = (lo + hi + 1) >> 1;
      if (idx[mid] <= rr) lo = mid;
      else hi = mid - 1;
    }
    const int local = s - lo;
    if (local >= 0 && local < MAX_SUB)
      sum += ws[((size_t)bb * MAX_SUB + local) * D_FEAT + t];
  }
  out[(size_t)s * D_FEAT + t] = fmaxf(sum / (float)(end - start), 0.f);
}

extern "C" void kernel_launch(void* const* d_in, const int* in_sizes, int n_in,
                              void* d_out, int out_size, void* d_ws,
                              size_t ws_size, hipStream_t stream) {
  const f4* in = (const f4*)d_in[0];
  const int* idx = (const int*)d_in[1];
  float* out = (float*)d_out;
  float* ws = (float*)d_ws;  // 1024*4*512*4B = 8 MB

  const int num_nodes = in_sizes[0] / D_FEAT;  // 200000
  const int num_graphs = in_sizes[1];          // 1024

  const int nblocks = 1024;  // 4 equal chunks per CU
  const int rpb = (num_nodes + nblocks - 1) / nblocks;  // 196

  seg_accum_ws<<<dim3(nblocks), dim3(512), 0, stream>>>(in, idx, ws, num_nodes,
                                                        num_graphs, rpb);
  seg_gather<<<dim3(num_graphs), dim3(512), 0, stream>>>(ws, idx, out,
                                                         num_nodes, num_graphs,
                                                         rpb);
}